// Round 1
// baseline (2172.466 us; speedup 1.0000x reference)
//
#include <hip/hip_runtime.h>
#include <math.h>

#define N_NODES 100000
#define MEM_DIM 256
#define B 20000
#define DIVIDE 8
#define TR 16

// ws layout (float offsets)
#define WT_S_OFF 0
#define BIAS_S_OFF (512 * 512)
#define WT_F_OFF (BIAS_S_OFF + 512)
#define BIAS_F_OFF (WT_F_OFF + 768 * 1024)

__device__ __forceinline__ float fsigmoid(float x) {
    x = fminf(fmaxf(x, -30.f), 30.f);
    return 1.0f / (1.0f + __expf(-x));
}
__device__ __forceinline__ float ftanh(float x) {
    x = fminf(fmaxf(x, -15.f), 15.f);
    float e = __expf(2.f * x);
    return (e - 1.f) / (e + 1.f);
}

// Build interleaved weight for steps 0..6: Wt_s[k][c], k in [0,512), c in [0,512)
// c = 2j   -> gate_C arg col j : k<256: W_C[j][k]      ; k>=256: W_h[256+j][k-256]
// c = 2j+1 -> h_C   arg col j : k<256: W_C[256+j][k]  ; k>=256: W_h[768+j][k-256]
__global__ void prep_s(const float* __restrict__ Wc, const float* __restrict__ Wcb,
                       const float* __restrict__ Wh, const float* __restrict__ Whb,
                       float* __restrict__ ws) {
    int idx = blockIdx.x * 256 + threadIdx.x;   // 512*512 elements
    int k = idx >> 9, c = idx & 511;
    int j = c >> 1;
    int ish = c & 1;
    float v;
    if (k < 256) {
        int row = ish ? (256 + j) : j;
        v = Wc[row * 256 + k];
    } else {
        int row = ish ? (768 + j) : (256 + j);
        v = Wh[row * 256 + (k - 256)];
    }
    ws[WT_S_OFF + idx] = v;
    if (idx < 512) {
        int jj = idx >> 1;
        float b = (idx & 1) ? (Wcb[256 + jj] + Whb[768 + jj])
                            : (Wcb[jj] + Whb[256 + jj]);
        ws[BIAS_S_OFF + idx] = b;
    }
}

// Final-step interleaved weight: Wt_f[k][c], k in [0,768), c in [0,1024)
// c = 4j+0 gc: k<256: W_C[j][k];     k<512: W_h[256+j][k-256]; else 0
// c = 4j+1 hc: k<256: W_C[256+j][k]; k<512: W_h[768+j][k-256]; else 0
// c = 4j+2 gd: k<256: 0;             k<512: W_h[j][k-256];     else W_D[j][k-512]
// c = 4j+3 hd: k<256: 0;             k<512: W_h[512+j][k-256]; else W_D[256+j][k-512]
__global__ void prep_f(const float* __restrict__ Wc, const float* __restrict__ Wcb,
                       const float* __restrict__ Wd, const float* __restrict__ Wdb,
                       const float* __restrict__ Wh, const float* __restrict__ Whb,
                       float* __restrict__ ws) {
    int idx = blockIdx.x * 256 + threadIdx.x;   // 768*1024 elements
    int k = idx >> 10, c = idx & 1023;
    int j = c >> 2, sel = c & 3;
    float v = 0.f;
    if (k < 256) {
        if (sel == 0) v = Wc[j * 256 + k];
        else if (sel == 1) v = Wc[(256 + j) * 256 + k];
    } else if (k < 512) {
        int kk = k - 256;
        int row = (sel == 0) ? (256 + j) : (sel == 1) ? (768 + j) : (sel == 2) ? j : (512 + j);
        v = Wh[row * 256 + kk];
    } else {
        int kk = k - 512;
        if (sel == 2) v = Wd[j * 256 + kk];
        else if (sel == 3) v = Wd[(256 + j) * 256 + kk];
    }
    ws[WT_F_OFF + idx] = v;
    if (idx < 1024) {
        int jj = idx >> 2, s = idx & 3;
        float b = (s == 0) ? (Wcb[jj] + Whb[256 + jj])
                : (s == 1) ? (Wcb[256 + jj] + Whb[768 + jj])
                : (s == 2) ? (Wdb[jj] + Whb[jj])
                           : (Wdb[256 + jj] + Whb[512 + jj]);
        ws[BIAS_F_OFF + idx] = b;
    }
}

// Steps 0..6: one block = 16 rows, 128 threads, each thread owns 4 output cols (c=4*tid).
__global__ __launch_bounds__(128) void step_kernel(
        float* __restrict__ mem, const float* __restrict__ msg,
        const int* __restrict__ ids, const float* __restrict__ Wt,
        const float* __restrict__ bias) {
    __shared__ float As[TR * 512];   // row: [msg(256) | m(256)]  32 KB
    __shared__ int sIds[TR];
    int tid = threadIdx.x;
    int r0 = blockIdx.x * TR;
    if (tid < TR) sIds[tid] = ids[r0 + tid];

    float4* As4 = (float4*)As;
    const float4* msg4 = (const float4*)(msg + (size_t)r0 * 256);
    for (int i = tid; i < TR * 64; i += 128) {
        int r = i >> 6, q = i & 63;
        As4[r * 128 + q] = msg4[r * 64 + q];
    }
    __syncthreads();   // sIds visible
    const float4* mem4 = (const float4*)mem;
    for (int i = tid; i < TR * 64; i += 128) {
        int r = i >> 6, q = i & 63;
        As4[r * 128 + 64 + q] = mem4[(size_t)sIds[r] * 64 + q];
    }
    __syncthreads();

    float acc0[TR], acc1[TR], acc2[TR], acc3[TR];
#pragma unroll
    for (int r = 0; r < TR; r++) { acc0[r] = acc1[r] = acc2[r] = acc3[r] = 0.f; }

    const float4* Wt4 = (const float4*)Wt;   // [k][512] -> k*128 + tid
    for (int k0 = 0; k0 < 512; k0 += 4) {
        float4 w0 = Wt4[(k0 + 0) * 128 + tid];
        float4 w1 = Wt4[(k0 + 1) * 128 + tid];
        float4 w2 = Wt4[(k0 + 2) * 128 + tid];
        float4 w3 = Wt4[(k0 + 3) * 128 + tid];
#pragma unroll
        for (int r = 0; r < TR; r++) {
            float4 a = As4[r * 128 + (k0 >> 2)];
            acc0[r] += a.x * w0.x + a.y * w1.x + a.z * w2.x + a.w * w3.x;
            acc1[r] += a.x * w0.y + a.y * w1.y + a.z * w2.y + a.w * w3.y;
            acc2[r] += a.x * w0.z + a.y * w1.z + a.z * w2.z + a.w * w3.z;
            acc3[r] += a.x * w0.w + a.y * w1.w + a.z * w2.w + a.w * w3.w;
        }
    }

    float4 bb = ((const float4*)bias)[tid];
    int j0 = tid * 2;
#pragma unroll
    for (int r = 0; r < TR; r++) {
        float g0 = fsigmoid(acc0[r] + bb.x);
        float h0 = ftanh(acc1[r] + bb.y);
        float g1 = fsigmoid(acc2[r] + bb.z);
        float h1 = ftanh(acc3[r] + bb.w);
        float m0 = As[r * 512 + 256 + j0];
        float m1 = As[r * 512 + 256 + j0 + 1];
        float2 nv = make_float2((1.f - g0) * h0 + g0 * m0,
                                (1.f - g1) * h1 + g1 * m1);
        *(float2*)(mem + (size_t)sIds[r] * 256 + j0) = nv;
    }
}

// Final step: 16 rows, 256 threads, each thread owns output col group j = tid.
__global__ __launch_bounds__(256) void final_kernel(
        float* __restrict__ mem, const float* __restrict__ msg,
        const int* __restrict__ ids, const float* __restrict__ dtdg,
        const float* __restrict__ Wt, const float* __restrict__ bias) {
    __shared__ float As[TR * 768];   // row: [msg(256) | m(256) | d(256)]  48 KB
    __shared__ int sIds[TR];
    int tid = threadIdx.x;
    int r0 = blockIdx.x * TR;
    if (tid < TR) sIds[tid] = ids[r0 + tid];

    float4* As4 = (float4*)As;
    const float4* msg4 = (const float4*)(msg + (size_t)r0 * 256);
    for (int i = tid; i < TR * 64; i += 256) {
        int r = i >> 6, q = i & 63;
        As4[r * 192 + q] = msg4[r * 64 + q];
    }
    __syncthreads();   // sIds visible
    const float4* mem4 = (const float4*)mem;
    const float4* dt4 = (const float4*)dtdg;
    for (int i = tid; i < TR * 64; i += 256) {
        int r = i >> 6, q = i & 63;
        As4[r * 192 + 64 + q] = mem4[(size_t)sIds[r] * 64 + q];
    }
    for (int i = tid; i < TR * 64; i += 256) {
        int r = i >> 6, q = i & 63;
        As4[r * 192 + 128 + q] = dt4[(size_t)sIds[r] * 64 + q];
    }
    __syncthreads();

    float acc0[TR], acc1[TR], acc2[TR], acc3[TR];
#pragma unroll
    for (int r = 0; r < TR; r++) { acc0[r] = acc1[r] = acc2[r] = acc3[r] = 0.f; }

    const float4* Wt4 = (const float4*)Wt;   // [k][1024] -> k*256 + tid
    // k < 256: only gc (x) and hc (y) columns are nonzero
    for (int k0 = 0; k0 < 256; k0 += 4) {
        float4 w0 = Wt4[(k0 + 0) * 256 + tid];
        float4 w1 = Wt4[(k0 + 1) * 256 + tid];
        float4 w2 = Wt4[(k0 + 2) * 256 + tid];
        float4 w3 = Wt4[(k0 + 3) * 256 + tid];
#pragma unroll
        for (int r = 0; r < TR; r++) {
            float4 a = As4[r * 192 + (k0 >> 2)];
            acc0[r] += a.x * w0.x + a.y * w1.x + a.z * w2.x + a.w * w3.x;
            acc1[r] += a.x * w0.y + a.y * w1.y + a.z * w2.y + a.w * w3.y;
        }
    }
    // 256 <= k < 512: all four columns
    for (int k0 = 256; k0 < 512; k0 += 4) {
        float4 w0 = Wt4[(k0 + 0) * 256 + tid];
        float4 w1 = Wt4[(k0 + 1) * 256 + tid];
        float4 w2 = Wt4[(k0 + 2) * 256 + tid];
        float4 w3 = Wt4[(k0 + 3) * 256 + tid];
#pragma unroll
        for (int r = 0; r < TR; r++) {
            float4 a = As4[r * 192 + (k0 >> 2)];
            acc0[r] += a.x * w0.x + a.y * w1.x + a.z * w2.x + a.w * w3.x;
            acc1[r] += a.x * w0.y + a.y * w1.y + a.z * w2.y + a.w * w3.y;
            acc2[r] += a.x * w0.z + a.y * w1.z + a.z * w2.z + a.w * w3.z;
            acc3[r] += a.x * w0.w + a.y * w1.w + a.z * w2.w + a.w * w3.w;
        }
    }
    // k >= 512: only gd (z) and hd (w) columns
    for (int k0 = 512; k0 < 768; k0 += 4) {
        float4 w0 = Wt4[(k0 + 0) * 256 + tid];
        float4 w1 = Wt4[(k0 + 1) * 256 + tid];
        float4 w2 = Wt4[(k0 + 2) * 256 + tid];
        float4 w3 = Wt4[(k0 + 3) * 256 + tid];
#pragma unroll
        for (int r = 0; r < TR; r++) {
            float4 a = As4[r * 192 + (k0 >> 2)];
            acc2[r] += a.x * w0.z + a.y * w1.z + a.z * w2.z + a.w * w3.z;
            acc3[r] += a.x * w0.w + a.y * w1.w + a.z * w2.w + a.w * w3.w;
        }
    }

    float4 bb = ((const float4*)bias)[tid];
#pragma unroll
    for (int r = 0; r < TR; r++) {
        float gc = fsigmoid(acc0[r] + bb.x);
        float hc = ftanh(acc1[r] + bb.y);
        float gd = fsigmoid(acc2[r] + bb.z);
        float hd = ftanh(acc3[r] + bb.w);
        float m = As[r * 768 + 256 + tid];
        mem[(size_t)sIds[r] * 256 + tid] =
            0.5f * (gd * hd + gc * hc + (2.f - gd - gc) * m);
    }
}

extern "C" void kernel_launch(void* const* d_in, const int* in_sizes, int n_in,
                              void* d_out, int out_size, void* d_ws, size_t ws_size,
                              hipStream_t stream) {
    (void)in_sizes; (void)n_in; (void)out_size; (void)ws_size;
    const float* memory = (const float*)d_in[0];
    const int* node_ids = (const int*)d_in[1];
    const float* messages = (const float*)d_in[2];
    const float* dtdg = (const float*)d_in[3];
    const float* Wc = (const float*)d_in[4];
    const float* Wcb = (const float*)d_in[5];
    const float* Wd = (const float*)d_in[6];
    const float* Wdb = (const float*)d_in[7];
    const float* Wh = (const float*)d_in[8];
    const float* Whb = (const float*)d_in[9];
    float* mem = (float*)d_out;
    float* ws = (float*)d_ws;

    // working memory = d_out, seeded from the pristine input
    hipMemcpyAsync(mem, memory, (size_t)N_NODES * MEM_DIM * sizeof(float),
                   hipMemcpyDeviceToDevice, stream);

    prep_s<<<512 * 512 / 256, 256, 0, stream>>>(Wc, Wcb, Wh, Whb, ws);
    prep_f<<<768 * 1024 / 256, 256, 0, stream>>>(Wc, Wcb, Wd, Wdb, Wh, Whb, ws);

    for (int t = 0; t < DIVIDE - 1; t++) {
        step_kernel<<<B / TR, 128, 0, stream>>>(
            mem, messages + (size_t)t * B * 256, node_ids + (size_t)t * B,
            ws + WT_S_OFF, ws + BIAS_S_OFF);
    }
    final_kernel<<<B / TR, 256, 0, stream>>>(
        mem, messages + (size_t)(DIVIDE - 1) * B * 256,
        node_ids + (size_t)(DIVIDE - 1) * B, dtdg,
        ws + WT_F_OFF, ws + BIAS_F_OFF);
}

// Round 2
// 1096.005 us; speedup vs baseline: 1.9822x; 1.9822x over previous
//
#include <hip/hip_runtime.h>
#include <math.h>

#define N_NODES 100000
#define B 20000
#define DIVIDE 8

typedef __attribute__((ext_vector_type(8))) short bf16x8;
typedef __attribute__((ext_vector_type(4))) float f32x4;

// ws byte offsets
#define BPS_BYTES (16 * 32 * 64 * 16)        // 512 KB  (steps + final C-part weights)
#define BPF_BYTES (24 * 64 * 64 * 16)        // 1.5 MB  (final fused weights)
#define BIAS_S_BYTE (BPS_BYTES + BPF_BYTES)
#define BIAS_F_BYTE (BIAS_S_BYTE + 512 * 4)

__device__ __forceinline__ float fsigmoid(float x) {
    x = fminf(fmaxf(x, -30.f), 30.f);
    return 1.f / (1.f + __expf(-x));
}
__device__ __forceinline__ float ftanh(float x) {
    x = fminf(fmaxf(x, -15.f), 15.f);
    float e = __expf(2.f * x);
    return (e - 1.f) / (e + 1.f);
}
__device__ __forceinline__ short f2bf(float v) {   // RNE float->bf16 bits
    unsigned u = __builtin_bit_cast(unsigned, v);
    u += 0x7FFFu + ((u >> 16) & 1u);
    return (short)(u >> 16);
}
__device__ __forceinline__ bf16x8 cvt8(float4 a, float4 b) {
    bf16x8 r;
    r[0] = f2bf(a.x); r[1] = f2bf(a.y); r[2] = f2bf(a.z); r[3] = f2bf(a.w);
    r[4] = f2bf(b.x); r[5] = f2bf(b.y); r[6] = f2bf(b.z); r[7] = f2bf(b.w);
    return r;
}

// ---------------- weight prep: b-fragment-major bf16 ----------------
// Bp entry (ks, ct, lane): 8 bf16 = W'[k0+j][c], k0 = ks*32+(lane>>4)*8,
// c = ct*16+(lane&15).  mfma b-frag: B[k][n], n=lane&15, k=(lane>>4)*8+j.

// W'_s[k][c] (steps / final-C): c<256 gate col c, c>=256 h col c-256
__global__ void prep_bps(const float* __restrict__ Wc, const float* __restrict__ Wcb,
                         const float* __restrict__ Wh, const float* __restrict__ Whb,
                         short* __restrict__ bps, float* __restrict__ bias) {
    int idx = blockIdx.x * 256 + threadIdx.x;    // 16*32*64 = 32768
    int ks = idx >> 11;
    int ct = (idx >> 6) & 31;
    int lane = idx & 63;
    int k0 = ks * 32 + ((lane >> 4) << 3);
    int c = ct * 16 + (lane & 15);
    int j = c & 255;
    bool isH = c >= 256;
    bf16x8 o;
#pragma unroll
    for (int t = 0; t < 8; t++) {
        int k = k0 + t;
        float v;
        if (k < 256) v = Wc[(size_t)(isH ? 256 + j : j) * 256 + k];
        else         v = Wh[(size_t)(isH ? 768 + j : 256 + j) * 256 + (k - 256)];
        o[t] = f2bf(v);
    }
    *(bf16x8*)(bps + (size_t)idx * 8) = o;
    if (idx < 512) {
        float b = (idx < 256) ? (Wcb[idx] + Whb[256 + idx])
                              : (Wcb[256 + (idx - 256)] + Whb[768 + (idx - 256)]);
        bias[idx] = b;
    }
}

// W'_f[k][c] (final fused): c>>8 = sel (0 gc, 1 hc, 2 gd, 3 hd), j=c&255
// k<256: msg block; 256..511: mem block; 512..767: dtdg block
__global__ void prep_bpf(const float* __restrict__ Wc, const float* __restrict__ Wcb,
                         const float* __restrict__ Wd, const float* __restrict__ Wdb,
                         const float* __restrict__ Wh, const float* __restrict__ Whb,
                         short* __restrict__ bpf, float* __restrict__ bias) {
    int idx = blockIdx.x * 256 + threadIdx.x;    // 24*64*64 = 98304
    int ks = idx >> 12;
    int ct = (idx >> 6) & 63;
    int lane = idx & 63;
    int k0 = ks * 32 + ((lane >> 4) << 3);
    int c = ct * 16 + (lane & 15);
    int sel = c >> 8, j = c & 255;
    bf16x8 o;
#pragma unroll
    for (int t = 0; t < 8; t++) {
        int k = k0 + t;
        float v = 0.f;
        if (k < 256) {
            if (sel == 0) v = Wc[(size_t)j * 256 + k];
            else if (sel == 1) v = Wc[(size_t)(256 + j) * 256 + k];
        } else if (k < 512) {
            int kk = k - 256;
            int row = (sel == 0) ? (256 + j) : (sel == 1) ? (768 + j)
                    : (sel == 2) ? j : (512 + j);
            v = Wh[(size_t)row * 256 + kk];
        } else {
            int kk = k - 512;
            if (sel == 2) v = Wd[(size_t)j * 256 + kk];
            else if (sel == 3) v = Wd[(size_t)(256 + j) * 256 + kk];
        }
        o[t] = f2bf(v);
    }
    *(bf16x8*)(bpf + (size_t)idx * 8) = o;
    if (idx < 1024) {
        int jj = idx & 255, s = idx >> 8;
        float b = (s == 0) ? (Wcb[jj] + Whb[256 + jj])
                : (s == 1) ? (Wcb[256 + jj] + Whb[768 + jj])
                : (s == 2) ? (Wdb[jj] + Whb[jj])
                           : (Wdb[256 + jj] + Whb[512 + jj]);
        bias[idx] = b;
    }
}

// ---------------- steps 0..6: block = 64 rows x 256 out cols ----------------
// wave q handles out cols [q*64, q*64+64): 4 gate tiles + 4 h tiles x 4 row tiles
__global__ __launch_bounds__(256) void step_mfma(
        float* __restrict__ mem, const float* __restrict__ msg,
        const int* __restrict__ ids,
        const bf16x8* __restrict__ Bp, const float* __restrict__ bias) {
    __shared__ int sIds[64];
    int tid = threadIdx.x;
    int lane = tid & 63;
    int q = tid >> 6;
    int r0 = blockIdx.x * 64;
    if (tid < 64) sIds[tid] = ids[min(r0 + tid, B - 1)];
    __syncthreads();

    int cl = lane & 15, quad = lane >> 4;
    int koff = quad * 8;

    const float* arow[4];
    const float* mrow[4];
#pragma unroll
    for (int rt = 0; rt < 4; rt++) {
        int rowA = min(r0 + rt * 16 + cl, B - 1);
        arow[rt] = msg + (size_t)rowA * 256 + koff;
        mrow[rt] = mem + (size_t)sIds[rt * 16 + cl] * 256 + koff;
    }

    f32x4 accG[4][4] = {{{0.f}}};
    f32x4 accH[4][4] = {{{0.f}}};
    const bf16x8* bp = Bp + lane;

    for (int ks = 0; ks < 16; ks++) {
        bf16x8 a[4];
#pragma unroll
        for (int rt = 0; rt < 4; rt++) {
            const float* s = (ks < 8) ? (arow[rt] + ks * 32) : (mrow[rt] + (ks - 8) * 32);
            float4 a0 = *(const float4*)s;
            float4 a1 = *(const float4*)(s + 4);
            a[rt] = cvt8(a0, a1);
        }
        int base = ks * 32 * 64;
#pragma unroll
        for (int t = 0; t < 4; t++) {
            bf16x8 bg = bp[base + (q * 4 + t) * 64];
            bf16x8 bh = bp[base + (16 + q * 4 + t) * 64];
#pragma unroll
            for (int rt = 0; rt < 4; rt++) {
                accG[rt][t] = __builtin_amdgcn_mfma_f32_16x16x32_bf16(a[rt], bg, accG[rt][t], 0, 0, 0);
                accH[rt][t] = __builtin_amdgcn_mfma_f32_16x16x32_bf16(a[rt], bh, accH[rt][t], 0, 0, 0);
            }
        }
    }
    __syncthreads();   // all waves' gathered mem reads done before epilogue writes

#pragma unroll
    for (int t = 0; t < 4; t++) {
        int col = q * 64 + t * 16 + cl;
        float bg = bias[col], bh = bias[256 + col];
#pragma unroll
        for (int rt = 0; rt < 4; rt++) {
#pragma unroll
            for (int r = 0; r < 4; r++) {
                int row = r0 + rt * 16 + quad * 4 + r;
                if (row < B) {
                    int id = sIds[rt * 16 + quad * 4 + r];
                    float* p = mem + (size_t)id * 256 + col;
                    float m = *p;
                    float g = fsigmoid(accG[rt][t][r] + bg);
                    float h = ftanh(accH[rt][t][r] + bh);
                    *p = (1.f - g) * h + g * m;
                }
            }
        }
    }
}

// ---------------- final fused step: block = 32 rows x 256 out cols ----------------
__global__ __launch_bounds__(256) void final_mfma(
        float* __restrict__ mem, const float* __restrict__ msg,
        const int* __restrict__ ids, const float* __restrict__ dtdg,
        const bf16x8* __restrict__ Bp, const float* __restrict__ bias) {
    __shared__ int sIds[32];
    int tid = threadIdx.x;
    int lane = tid & 63;
    int q = tid >> 6;
    int r0 = blockIdx.x * 32;
    if (tid < 32) sIds[tid] = ids[r0 + tid];
    __syncthreads();

    int cl = lane & 15, quad = lane >> 4;
    int koff = quad * 8;

    const float* arow[2];
    const float* mrow[2];
    const float* drow[2];
#pragma unroll
    for (int rt = 0; rt < 2; rt++) {
        int rowA = r0 + rt * 16 + cl;
        int id = sIds[rt * 16 + cl];
        arow[rt] = msg + (size_t)rowA * 256 + koff;
        mrow[rt] = mem + (size_t)id * 256 + koff;
        drow[rt] = dtdg + (size_t)id * 256 + koff;
    }

    f32x4 aGC[2][4] = {{{0.f}}}, aHC[2][4] = {{{0.f}}};
    f32x4 aGD[2][4] = {{{0.f}}}, aHD[2][4] = {{{0.f}}};
    const bf16x8* bp = Bp + lane;

    for (int ks = 0; ks < 8; ks++) {           // msg block -> gc,hc
        bf16x8 a[2];
#pragma unroll
        for (int rt = 0; rt < 2; rt++) {
            const float* s = arow[rt] + ks * 32;
            a[rt] = cvt8(*(const float4*)s, *(const float4*)(s + 4));
        }
        int base = ks * 64 * 64;
#pragma unroll
        for (int t = 0; t < 4; t++) {
            bf16x8 b0 = bp[base + (q * 4 + t) * 64];
            bf16x8 b1 = bp[base + (16 + q * 4 + t) * 64];
#pragma unroll
            for (int rt = 0; rt < 2; rt++) {
                aGC[rt][t] = __builtin_amdgcn_mfma_f32_16x16x32_bf16(a[rt], b0, aGC[rt][t], 0, 0, 0);
                aHC[rt][t] = __builtin_amdgcn_mfma_f32_16x16x32_bf16(a[rt], b1, aHC[rt][t], 0, 0, 0);
            }
        }
    }
    for (int ks = 8; ks < 16; ks++) {          // mem block -> all four
        bf16x8 a[2];
#pragma unroll
        for (int rt = 0; rt < 2; rt++) {
            const float* s = mrow[rt] + (ks - 8) * 32;
            a[rt] = cvt8(*(const float4*)s, *(const float4*)(s + 4));
        }
        int base = ks * 64 * 64;
#pragma unroll
        for (int t = 0; t < 4; t++) {
            bf16x8 b0 = bp[base + (q * 4 + t) * 64];
            bf16x8 b1 = bp[base + (16 + q * 4 + t) * 64];
            bf16x8 b2 = bp[base + (32 + q * 4 + t) * 64];
            bf16x8 b3 = bp[base + (48 + q * 4 + t) * 64];
#pragma unroll
            for (int rt = 0; rt < 2; rt++) {
                aGC[rt][t] = __builtin_amdgcn_mfma_f32_16x16x32_bf16(a[rt], b0, aGC[rt][t], 0, 0, 0);
                aHC[rt][t] = __builtin_amdgcn_mfma_f32_16x16x32_bf16(a[rt], b1, aHC[rt][t], 0, 0, 0);
                aGD[rt][t] = __builtin_amdgcn_mfma_f32_16x16x32_bf16(a[rt], b2, aGD[rt][t], 0, 0, 0);
                aHD[rt][t] = __builtin_amdgcn_mfma_f32_16x16x32_bf16(a[rt], b3, aHD[rt][t], 0, 0, 0);
            }
        }
    }
    for (int ks = 16; ks < 24; ks++) {         // dtdg block -> gd,hd
        bf16x8 a[2];
#pragma unroll
        for (int rt = 0; rt < 2; rt++) {
            const float* s = drow[rt] + (ks - 16) * 32;
            a[rt] = cvt8(*(const float4*)s, *(const float4*)(s + 4));
        }
        int base = ks * 64 * 64;
#pragma unroll
        for (int t = 0; t < 4; t++) {
            bf16x8 b2 = bp[base + (32 + q * 4 + t) * 64];
            bf16x8 b3 = bp[base + (48 + q * 4 + t) * 64];
#pragma unroll
            for (int rt = 0; rt < 2; rt++) {
                aGD[rt][t] = __builtin_amdgcn_mfma_f32_16x16x32_bf16(a[rt], b2, aGD[rt][t], 0, 0, 0);
                aHD[rt][t] = __builtin_amdgcn_mfma_f32_16x16x32_bf16(a[rt], b3, aHD[rt][t], 0, 0, 0);
            }
        }
    }
    __syncthreads();

#pragma unroll
    for (int t = 0; t < 4; t++) {
        int col = q * 64 + t * 16 + cl;
        float b0 = bias[col], b1 = bias[256 + col];
        float b2 = bias[512 + col], b3 = bias[768 + col];
#pragma unroll
        for (int rt = 0; rt < 2; rt++) {
#pragma unroll
            for (int r = 0; r < 4; r++) {
                int row = r0 + rt * 16 + quad * 4 + r;
                int id = sIds[rt * 16 + quad * 4 + r];
                float* p = mem + (size_t)id * 256 + col;
                float m = *p;
                float gc = fsigmoid(aGC[rt][t][r] + b0);
                float hc = ftanh(aHC[rt][t][r] + b1);
                float gd = fsigmoid(aGD[rt][t][r] + b2);
                float hd = ftanh(aHD[rt][t][r] + b3);
                *p = m + 0.5f * (gc * (hc - m) + gd * (hd - m));
                (void)row;
            }
        }
    }
}

extern "C" void kernel_launch(void* const* d_in, const int* in_sizes, int n_in,
                              void* d_out, int out_size, void* d_ws, size_t ws_size,
                              hipStream_t stream) {
    (void)in_sizes; (void)n_in; (void)out_size; (void)ws_size;
    const float* memory = (const float*)d_in[0];
    const int* node_ids = (const int*)d_in[1];
    const float* messages = (const float*)d_in[2];
    const float* dtdg = (const float*)d_in[3];
    const float* Wc = (const float*)d_in[4];
    const float* Wcb = (const float*)d_in[5];
    const float* Wd = (const float*)d_in[6];
    const float* Wdb = (const float*)d_in[7];
    const float* Wh = (const float*)d_in[8];
    const float* Whb = (const float*)d_in[9];
    float* mem = (float*)d_out;
    char* ws = (char*)d_ws;

    short* bps = (short*)ws;
    short* bpf = (short*)(ws + BPS_BYTES);
    float* bias_s = (float*)(ws + BIAS_S_BYTE);
    float* bias_f = (float*)(ws + BIAS_F_BYTE);

    hipMemcpyAsync(mem, memory, (size_t)N_NODES * 256 * sizeof(float),
                   hipMemcpyDeviceToDevice, stream);

    prep_bps<<<128, 256, 0, stream>>>(Wc, Wcb, Wh, Whb, bps, bias_s);
    prep_bpf<<<384, 256, 0, stream>>>(Wc, Wcb, Wd, Wdb, Wh, Whb, bpf, bias_f);

    for (int t = 0; t < DIVIDE - 1; t++) {
        step_mfma<<<(B + 63) / 64, 256, 0, stream>>>(
            mem, messages + (size_t)t * B * 256, node_ids + (size_t)t * B,
            (const bf16x8*)bps, bias_s);
    }
    final_mfma<<<B / 32, 256, 0, stream>>>(
        mem, messages + (size_t)(DIVIDE - 1) * B * 256,
        node_ids + (size_t)(DIVIDE - 1) * B, dtdg,
        (const bf16x8*)bpf, bias_f);
}